// Round 13
// baseline (1025.822 us; speedup 1.0000x reference)
//
#include <hip/hip_runtime.h>
#include <math.h>

namespace {

typedef short bf8_t __attribute__((ext_vector_type(8)));   // 8 bf16 payloads
typedef float f32x4 __attribute__((ext_vector_type(4)));
typedef unsigned short u16;

constexpr int kB = 2, kS = 4096, kD = 512, kH = 8, kBH = 16;
constexpr float kScale = 0.125f;  // 1/sqrt(64)

// Truncation-based fp32 -> bf16 hi/lo split. hi+lo reconstructs x to ~2^-17.
__device__ __forceinline__ void split2(float x, u16& hi, u16& lo) {
  const unsigned u = __float_as_uint(x);
  hi = (u16)(u >> 16);
  const float r = x - __uint_as_float(u & 0xFFFF0000u);
  lo = (u16)(__float_as_uint(r) >> 16);
}

// ---------------------------------------------------------------------------
// split: fp32[n] -> bf16 hi[n], lo[n].  One float4 per thread.
// ---------------------------------------------------------------------------
__global__ __launch_bounds__(256) void split_kernel(
    const float* __restrict__ src, u16* __restrict__ dhi,
    u16* __restrict__ dlo) {
  const size_t i4 = ((size_t)blockIdx.x * 256 + threadIdx.x) * 4;
  const float4 v = *(const float4*)&src[i4];
  union { u16 u[4]; uint2 q; } h, l;
  split2(v.x, h.u[0], l.u[0]);
  split2(v.y, h.u[1], l.u[1]);
  split2(v.z, h.u[2], l.u[2]);
  split2(v.w, h.u[3], l.u[3]);
  *(uint2*)&dhi[i4] = h.q;
  *(uint2*)&dlo[i4] = l.q;
}

// ---------------------------------------------------------------------------
// splitT: W[512k][512n] fp32 -> Wt hi/lo [n][k] bf16.  64x64 LDS transpose.
// ---------------------------------------------------------------------------
__global__ __launch_bounds__(256) void splitT_kernel(
    const float* __restrict__ W, u16* __restrict__ whi,
    u16* __restrict__ wlo) {
  __shared__ float Ls[64][68];
  const int t = threadIdx.x;
  const int n0 = blockIdx.x * 64, k0 = blockIdx.y * 64;
#pragma unroll
  for (int i = 0; i < 4; ++i) {
    const int kl = (t >> 4) + i * 16;
    const int n4 = (t & 15) * 4;
    const float4 v = *(const float4*)&W[(size_t)(k0 + kl) * kD + n0 + n4];
    Ls[kl][n4 + 0] = v.x; Ls[kl][n4 + 1] = v.y;
    Ls[kl][n4 + 2] = v.z; Ls[kl][n4 + 3] = v.w;
  }
  __syncthreads();
#pragma unroll
  for (int i = 0; i < 4; ++i) {
    const int nl = (t >> 4) + i * 16;
    const int k4 = (t & 15) * 4;
    union { u16 u[4]; uint2 q; } h, l;
#pragma unroll
    for (int j = 0; j < 4; ++j) split2(Ls[k4 + j][nl], h.u[j], l.u[j]);
    *(uint2*)&whi[(size_t)(n0 + nl) * kD + k0 + k4] = h.q;
    *(uint2*)&wlo[(size_t)(n0 + nl) * kD + k0 + k4] = l.q;
  }
}

// ---------------------------------------------------------------------------
// MFMA GEMM (bf16x3): C = A[M,512] @ W[512,512] + bias, A/Wt as hi+lo bf16.
// Wt is W^T [n][k].  Block 128m x 64n, 4 waves (each 32m x 64n), K-step 64.
// LDS tiles XOR-swizzled at 16B granularity: chunk c' = c ^ (row&7).
// MODE 0: per-head bf16 pairs  o[((b*H+h)*S+s)*64+dk]
// MODE 1: fp32 row-major       oF[m*512+n]
// ---------------------------------------------------------------------------
template <int MODE>
__global__ __launch_bounds__(256) void mfma_gemm_kernel(
    const u16* __restrict__ Ahi, const u16* __restrict__ Alo,
    const u16* __restrict__ Whi, const u16* __restrict__ Wlo,
    const float* __restrict__ bias, u16* __restrict__ oHi,
    u16* __restrict__ oLo, float* __restrict__ oF) {
  __shared__ u16 gsm[24576];  // Ah 8192 | Al 8192 | Wh 4096 | Wl 4096 (48KB)
  u16* AhS = gsm;
  u16* AlS = gsm + 8192;
  u16* WhS = gsm + 16384;
  u16* WlS = gsm + 20480;

  const int t = threadIdx.x;
  const int w = t >> 6, l = t & 63;
  const int lr = l & 15, lg = l >> 4;
  const int m0 = blockIdx.y * 128;
  const int n0 = blockIdx.x * 64;

  f32x4 acc[2][4];
  {
    const f32x4 z = {0.f, 0.f, 0.f, 0.f};
#pragma unroll
    for (int mt = 0; mt < 2; ++mt)
#pragma unroll
      for (int nt = 0; nt < 4; ++nt) acc[mt][nt] = z;
  }

  uint4 rAh[4], rAl[4], rWh[2], rWl[2];
#pragma unroll
  for (int i = 0; i < 4; ++i) {  // prologue: k-step 0
    const int p = t + i * 256, row = p >> 3, c = p & 7;
    rAh[i] = *(const uint4*)&Ahi[(size_t)(m0 + row) * kD + c * 8];
    rAl[i] = *(const uint4*)&Alo[(size_t)(m0 + row) * kD + c * 8];
  }
#pragma unroll
  for (int i = 0; i < 2; ++i) {
    const int p = t + i * 256, row = p >> 3, c = p & 7;
    rWh[i] = *(const uint4*)&Whi[(size_t)(n0 + row) * kD + c * 8];
    rWl[i] = *(const uint4*)&Wlo[(size_t)(n0 + row) * kD + c * 8];
  }

  for (int ks = 0; ks < 8; ++ks) {
    __syncthreads();
#pragma unroll
    for (int i = 0; i < 4; ++i) {
      const int p = t + i * 256, row = p >> 3, c = p & 7;
      const int ch = (row * 8 + (c ^ (row & 7))) * 8;
      *(uint4*)&AhS[ch] = rAh[i];
      *(uint4*)&AlS[ch] = rAl[i];
    }
#pragma unroll
    for (int i = 0; i < 2; ++i) {
      const int p = t + i * 256, row = p >> 3, c = p & 7;
      const int ch = (row * 8 + (c ^ (row & 7))) * 8;
      *(uint4*)&WhS[ch] = rWh[i];
      *(uint4*)&WlS[ch] = rWl[i];
    }
    __syncthreads();

    if (ks + 1 < 8) {
      const int kk = (ks + 1) * 64;
#pragma unroll
      for (int i = 0; i < 4; ++i) {
        const int p = t + i * 256, row = p >> 3, c = p & 7;
        rAh[i] = *(const uint4*)&Ahi[(size_t)(m0 + row) * kD + kk + c * 8];
        rAl[i] = *(const uint4*)&Alo[(size_t)(m0 + row) * kD + kk + c * 8];
      }
#pragma unroll
      for (int i = 0; i < 2; ++i) {
        const int p = t + i * 256, row = p >> 3, c = p & 7;
        rWh[i] = *(const uint4*)&Whi[(size_t)(n0 + row) * kD + kk + c * 8];
        rWl[i] = *(const uint4*)&Wlo[(size_t)(n0 + row) * kD + kk + c * 8];
      }
    }

#pragma unroll
    for (int kh = 0; kh < 2; ++kh) {
#pragma unroll
      for (int mt = 0; mt < 2; ++mt) {
        const int ar = w * 32 + mt * 16 + lr;
        const int au = (ar * 64 + ((kh * 32 + lg * 8) ^ ((ar & 7) * 8)));
        const bf8_t ah = *(const bf8_t*)&AhS[au];
        const bf8_t al = *(const bf8_t*)&AlS[au];
#pragma unroll
        for (int nt = 0; nt < 4; ++nt) {
          const int br = nt * 16 + lr;
          const int bu = (br * 64 + ((kh * 32 + lg * 8) ^ ((br & 7) * 8)));
          const bf8_t bh = *(const bf8_t*)&WhS[bu];
          const bf8_t bl = *(const bf8_t*)&WlS[bu];
          f32x4 a = acc[mt][nt];
          a = __builtin_amdgcn_mfma_f32_16x16x32_bf16(ah, bh, a, 0, 0, 0);
          a = __builtin_amdgcn_mfma_f32_16x16x32_bf16(ah, bl, a, 0, 0, 0);
          a = __builtin_amdgcn_mfma_f32_16x16x32_bf16(al, bh, a, 0, 0, 0);
          acc[mt][nt] = a;
        }
      }
    }
  }

  // epilogue: add bias, stage fp32 in LDS, coalesced store
  __syncthreads();
  float* smf = (float*)gsm;  // 128x64 fp32 = 32KB
#pragma unroll
  for (int nt = 0; nt < 4; ++nt) {
    const float bb = bias[n0 + nt * 16 + lr];
#pragma unroll
    for (int mt = 0; mt < 2; ++mt)
#pragma unroll
      for (int r = 0; r < 4; ++r)
        smf[(w * 32 + mt * 16 + lg * 4 + r) * 64 + nt * 16 + lr] =
            acc[mt][nt][r] + bb;
  }
  __syncthreads();
#pragma unroll
  for (int i = 0; i < 8; ++i) {
    const int p = t + i * 256;
    const int ml = p >> 4, n4 = (p & 15) * 4;
    const float4 v = *(const float4*)&smf[p * 4];
    if (MODE == 0) {
      const int m = m0 + ml;
      const int bh = (m >> 12) * kH + (n0 >> 6);
      const int s = m & (kS - 1);
      union { u16 u[4]; uint2 q; } h, lo;
      split2(v.x, h.u[0], lo.u[0]);
      split2(v.y, h.u[1], lo.u[1]);
      split2(v.z, h.u[2], lo.u[2]);
      split2(v.w, h.u[3], lo.u[3]);
      const size_t off = ((size_t)bh * kS + s) * 64 + n4;
      *(uint2*)&oHi[off] = h.q;
      *(uint2*)&oLo[off] = lo.q;
    } else {
      *(float4*)&oF[(size_t)(m0 + ml) * kD + n0 + n4] = v;
    }
  }
}

// ---------------------------------------------------------------------------
// colstats: Rl[bh][k] = 1 / sum_q exp(s[q,k]*scale).  K-frags persistent in
// regs; Q tiles LDS-staged (swizzled) with reg prefetch.  1024 blocks.
// ---------------------------------------------------------------------------
__global__ __launch_bounds__(256) void colstats_kernel(
    const u16* __restrict__ Qhi, const u16* __restrict__ Qlo,
    const u16* __restrict__ Khi, const u16* __restrict__ Klo,
    float* __restrict__ Rl) {
  __shared__ u16 qsm[8192];  // Qh 4096 | Ql 4096  (64q x 64d each)
  __shared__ float red[4][64];
  const int nid = (int)blockIdx.x;
  const int swz = (nid & 7) * 128 + (nid >> 3);
  const int bh = swz >> 6;
  const int k0 = (swz & 63) << 6;
  const int t = threadIdx.x;
  const int w = t >> 6, l = t & 63;
  const int lr = l & 15, lg = l >> 4;
  const size_t base = (size_t)bh * kS * 64;

  // persistent K fragments (B operand): 64 columns
  bf8_t kbh[4][2], kbl[4][2];
#pragma unroll
  for (int nt = 0; nt < 4; ++nt)
#pragma unroll
    for (int kh = 0; kh < 2; ++kh) {
      const size_t off =
          base + (size_t)(k0 + nt * 16 + lr) * 64 + kh * 32 + lg * 8;
      kbh[nt][kh] = *(const bf8_t*)&Khi[off];
      kbl[nt][kh] = *(const bf8_t*)&Klo[off];
    }

  float lsum[4] = {0.f, 0.f, 0.f, 0.f};

  uint4 rqh[2], rql[2];
#pragma unroll
  for (int i = 0; i < 2; ++i) {  // prologue: q-tile 0
    const int p = t + i * 256, row = p >> 3, c = p & 7;
    rqh[i] = *(const uint4*)&Qhi[base + (size_t)row * 64 + c * 8];
    rql[i] = *(const uint4*)&Qlo[base + (size_t)row * 64 + c * 8];
  }

  for (int qt = 0; qt < kS / 64; ++qt) {
    __syncthreads();
#pragma unroll
    for (int i = 0; i < 2; ++i) {
      const int p = t + i * 256, row = p >> 3, c = p & 7;
      const int ch = (row * 8 + (c ^ (row & 7))) * 8;
      *(uint4*)&qsm[ch] = rqh[i];
      *(uint4*)&qsm[4096 + ch] = rql[i];
    }
    __syncthreads();

    if (qt + 1 < kS / 64) {
      const size_t q0n = (size_t)(qt + 1) * 64;
#pragma unroll
      for (int i = 0; i < 2; ++i) {
        const int p = t + i * 256, row = p >> 3, c = p & 7;
        rqh[i] = *(const uint4*)&Qhi[base + (q0n + row) * 64 + c * 8];
        rql[i] = *(const uint4*)&Qlo[base + (q0n + row) * 64 + c * 8];
      }
    }

    bf8_t qah[2], qal[2];
#pragma unroll
    for (int kh = 0; kh < 2; ++kh) {
      const int ar = w * 16 + lr;
      const int au = ar * 64 + ((kh * 32 + lg * 8) ^ ((ar & 7) * 8));
      qah[kh] = *(const bf8_t*)&qsm[au];
      qal[kh] = *(const bf8_t*)&qsm[4096 + au];
    }
#pragma unroll
    for (int nt = 0; nt < 4; ++nt) {
      f32x4 a = {0.f, 0.f, 0.f, 0.f};
#pragma unroll
      for (int kh = 0; kh < 2; ++kh) {
        a = __builtin_amdgcn_mfma_f32_16x16x32_bf16(qah[kh], kbh[nt][kh], a, 0, 0, 0);
        a = __builtin_amdgcn_mfma_f32_16x16x32_bf16(qah[kh], kbl[nt][kh], a, 0, 0, 0);
        a = __builtin_amdgcn_mfma_f32_16x16x32_bf16(qal[kh], kbh[nt][kh], a, 0, 0, 0);
      }
#pragma unroll
      for (int r = 0; r < 4; ++r) lsum[nt] += __expf(a[r] * kScale);
    }
  }

#pragma unroll
  for (int nt = 0; nt < 4; ++nt) {
    float s = lsum[nt];
    s += __shfl_xor(s, 16, 64);
    s += __shfl_xor(s, 32, 64);
    lsum[nt] = s;
  }
  if (l < 16) {
#pragma unroll
    for (int nt = 0; nt < 4; ++nt) red[w][nt * 16 + l] = lsum[nt];
  }
  __syncthreads();
  if (t < 64) {
    const float s = red[0][t] + red[1][t] + red[2][t] + red[3][t];
    Rl[(size_t)bh * kS + k0 + t] = 1.0f / s;
  }
}

// ---------------------------------------------------------------------------
// vtrans_scale: Vrm fp32 [b*s][512] -> V' = V*Rl, transposed bf16 hi/lo
// [bh][dv][s].  Block: one bh x 64s x 64dv.
// ---------------------------------------------------------------------------
__global__ __launch_bounds__(256) void vtrans_kernel(
    const float* __restrict__ Vrm, const float* __restrict__ Rl,
    u16* __restrict__ Vsh, u16* __restrict__ Vsl) {
  __shared__ float Ls[64][68];
  __shared__ float rl[64];
  const int t = threadIdx.x;
  const int s0 = blockIdx.x * 64;
  const int bh = blockIdx.y;
  const int bI = bh >> 3, h = bh & 7;
#pragma unroll
  for (int i = 0; i < 4; ++i) {
    const int sl = (t >> 4) + i * 16;
    const int d4 = (t & 15) * 4;
    const float4 v =
        *(const float4*)&Vrm[(size_t)(bI * kS + s0 + sl) * kD + h * 64 + d4];
    Ls[sl][d4 + 0] = v.x; Ls[sl][d4 + 1] = v.y;
    Ls[sl][d4 + 2] = v.z; Ls[sl][d4 + 3] = v.w;
  }
  if (t < 64) rl[t] = Rl[(size_t)bh * kS + s0 + t];
  __syncthreads();
#pragma unroll
  for (int i = 0; i < 4; ++i) {
    const int d = (t >> 4) + i * 16;
    const int s4 = (t & 15) * 4;
    union { u16 u[4]; uint2 q; } h4, l4;
#pragma unroll
    for (int j = 0; j < 4; ++j)
      split2(Ls[s4 + j][d] * rl[s4 + j], h4.u[j], l4.u[j]);
    const size_t off = (size_t)(bh * 64 + d) * kS + s0 + s4;
    *(uint2*)&Vsh[off] = h4.q;
    *(uint2*)&Vsl[off] = l4.q;
  }
}

// ---------------------------------------------------------------------------
// attn: O = P·V', P = exp(s*scale) (1/l folded into V').  S^T orientation,
// P packed in-register into PV B-frags; V' k-permuted in LDS.  All LDS tiles
// [64][64] bf16, XOR-swizzled.  Emits bf16 hi/lo AttnOut for the out-GEMM.
// Block: 128 q-rows, 4 waves; grid 512 XCD-chunked.
// ---------------------------------------------------------------------------
__global__ __launch_bounds__(256) void attn_kernel(
    const u16* __restrict__ Qhi, const u16* __restrict__ Qlo,
    const u16* __restrict__ Khi, const u16* __restrict__ Klo,
    const u16* __restrict__ Vsh, const u16* __restrict__ Vsl,
    u16* __restrict__ AoHi, u16* __restrict__ AoLo) {
  __shared__ u16 smem[16384];  // KsH | KsL | VpH | VpL  (4 x 8KB)
  u16* KsH = smem;
  u16* KsL = smem + 4096;
  u16* VpH = smem + 8192;
  u16* VpL = smem + 12288;

  const int nid = (int)blockIdx.x;
  const int swz = (nid & 7) * 64 + (nid >> 3);
  const int bh = swz >> 5;
  const int q0 = (swz & 31) << 7;
  const int t = threadIdx.x;
  const int w = t >> 6, l = t & 63;
  const int lr = l & 15, lg = l >> 4;
  const size_t base = (size_t)bh * kS * 64;

  const int srow = t >> 3;
  const int sc = t & 7;
  const int sc8 = sc * 8;
  const int sub = sc & 3;
  const int posA = ((sc >> 2) << 5) + ((sub & 1) << 4) + ((sub >> 1) << 2);

  // persistent Q fragments (B operand): cols q = q0 + w*32 + nt*16 + lr
  bf8_t qh[2][2], ql[2][2];
#pragma unroll
  for (int nt = 0; nt < 2; ++nt) {
    const size_t qoff = base + (size_t)(q0 + w * 32 + nt * 16 + lr) * 64;
#pragma unroll
    for (int kh = 0; kh < 2; ++kh) {
      qh[nt][kh] = *(const bf8_t*)&Qhi[qoff + kh * 32 + lg * 8];
      ql[nt][kh] = *(const bf8_t*)&Qlo[qoff + kh * 32 + lg * 8];
    }
  }

  f32x4 acco[4][2];
  {
    const f32x4 z = {0.f, 0.f, 0.f, 0.f};
#pragma unroll
    for (int mt = 0; mt < 4; ++mt)
#pragma unroll
      for (int nt = 0; nt < 2; ++nt) acco[mt][nt] = z;
  }

  uint4 rkh[2], rkl[2], rvh[2], rvl[2];
#pragma unroll
  for (int ri = 0; ri < 2; ++ri) {  // prologue: tile 0
    const int row = srow + ri * 32;
    rkh[ri] = *(const uint4*)&Khi[base + (size_t)row * 64 + sc8];
    rkl[ri] = *(const uint4*)&Klo[base + (size_t)row * 64 + sc8];
    rvh[ri] = *(const uint4*)&Vsh[(size_t)(bh * 64 + row) * kS + sc8];
    rvl[ri] = *(const uint4*)&Vsl[(size_t)(bh * 64 + row) * kS + sc8];
  }

  for (int kt = 0; kt < kS / 64; ++kt) {
    __syncthreads();
#pragma unroll
    for (int ri = 0; ri < 2; ++ri) {
      const int row = srow + ri * 32;
      const int xs = (row & 7) * 8;
      *(uint4*)&KsH[(row * 64 + sc8) ^ xs] = rkh[ri];
      *(uint4*)&KsL[(row * 64 + sc8) ^ xs] = rkl[ri];
      uint2 a, b;
      a.x = rvh[ri].x; a.y = rvh[ri].y; b.x = rvh[ri].z; b.y = rvh[ri].w;
      *(uint2*)&VpH[(row * 64 + posA) ^ xs] = a;
      *(uint2*)&VpH[(row * 64 + posA + 8) ^ xs] = b;
      a.x = rvl[ri].x; a.y = rvl[ri].y; b.x = rvl[ri].z; b.y = rvl[ri].w;
      *(uint2*)&VpL[(row * 64 + posA) ^ xs] = a;
      *(uint2*)&VpL[(row * 64 + posA + 8) ^ xs] = b;
    }
    __syncthreads();

    if (kt + 1 < kS / 64) {  // prefetch next tile under compute
      const int k0n = (kt + 1) * 64;
#pragma unroll
      for (int ri = 0; ri < 2; ++ri) {
        const int row = srow + ri * 32;
        rkh[ri] = *(const uint4*)&Khi[base + (size_t)(k0n + row) * 64 + sc8];
        rkl[ri] = *(const uint4*)&Klo[base + (size_t)(k0n + row) * 64 + sc8];
        rvh[ri] = *(const uint4*)&Vsh[(size_t)(bh * 64 + row) * kS + k0n + sc8];
        rvl[ri] = *(const uint4*)&Vsl[(size_t)(bh * 64 + row) * kS + k0n + sc8];
      }
    }

    // ---- S^T = K·Q^T ----
    f32x4 accs[4][2];
#pragma unroll
    for (int mt = 0; mt < 4; ++mt) {
      bf8_t kfh[2], kfl[2];
#pragma unroll
      for (int kh = 0; kh < 2; ++kh) {
        const int ar = mt * 16 + lr;
        const int au = (ar * 64 + kh * 32 + lg * 8) ^ ((ar & 7) * 8);
        kfh[kh] = *(const bf8_t*)&KsH[au];
        kfl[kh] = *(const bf8_t*)&KsL[au];
      }
#pragma unroll
      for (int nt = 0; nt < 2; ++nt) {
        f32x4 a = {0.f, 0.f, 0.f, 0.f};
#pragma unroll
        for (int kh = 0; kh < 2; ++kh) {
          a = __builtin_amdgcn_mfma_f32_16x16x32_bf16(kfh[kh], qh[nt][kh], a, 0, 0, 0);
          a = __builtin_amdgcn_mfma_f32_16x16x32_bf16(kfh[kh], ql[nt][kh], a, 0, 0, 0);
          a = __builtin_amdgcn_mfma_f32_16x16x32_bf16(kfl[kh], qh[nt][kh], a, 0, 0, 0);
        }
        accs[mt][nt] = a;
      }
    }

    // ---- P = exp(s*scale), packed hi/lo into PV B-frags (k-slot order
    //      matches Vp's k-permutation) ----
    bf8_t ph[2][2], pl[2][2];
#pragma unroll
    for (int nt = 0; nt < 2; ++nt)
#pragma unroll
      for (int kh = 0; kh < 2; ++kh) {
        union { u16 u[8]; bf8_t v; } uh, ul;
#pragma unroll
        for (int r = 0; r < 4; ++r) {
          const float x0 = __expf(accs[2 * kh][nt][r] * kScale);
          split2(x0, uh.u[r], ul.u[r]);
          const float x1 = __expf(accs[2 * kh + 1][nt][r] * kScale);
          split2(x1, uh.u[4 + r], ul.u[4 + r]);
        }
        ph[nt][kh] = uh.v;
        pl[nt][kh] = ul.v;
      }

    // ---- O^T += V'^T · P^T ----
#pragma unroll
    for (int mt = 0; mt < 4; ++mt) {
      bf8_t vfh[2], vfl[2];
#pragma unroll
      for (int kh = 0; kh < 2; ++kh) {
        const int ar = mt * 16 + lr;
        const int au = (ar * 64 + kh * 32 + lg * 8) ^ ((ar & 7) * 8);
        vfh[kh] = *(const bf8_t*)&VpH[au];
        vfl[kh] = *(const bf8_t*)&VpL[au];
      }
#pragma unroll
      for (int nt = 0; nt < 2; ++nt) {
        f32x4 a = acco[mt][nt];
#pragma unroll
        for (int kh = 0; kh < 2; ++kh) {
          a = __builtin_amdgcn_mfma_f32_16x16x32_bf16(vfh[kh], ph[nt][kh], a, 0, 0, 0);
          a = __builtin_amdgcn_mfma_f32_16x16x32_bf16(vfh[kh], pl[nt][kh], a, 0, 0, 0);
          a = __builtin_amdgcn_mfma_f32_16x16x32_bf16(vfl[kh], ph[nt][kh], a, 0, 0, 0);
        }
        acco[mt][nt] = a;
      }
    }
  }

  // ---- epilogue: stage O fp32 in LDS, emit coalesced bf16 hi/lo ----
  __syncthreads();
  float* smf = (float*)smem;  // 128q x 64dv fp32 = 32KB
#pragma unroll
  for (int mt = 0; mt < 4; ++mt)
#pragma unroll
    for (int nt = 0; nt < 2; ++nt) {
      const int qv = w * 32 + nt * 16 + lr;
#pragma unroll
      for (int r = 0; r < 4; ++r)
        smf[qv * 64 + mt * 16 + lg * 4 + r] = acco[mt][nt][r];
    }
  __syncthreads();
  const int bI = bh >> 3, h = bh & 7;
#pragma unroll
  for (int i = 0; i < 8; ++i) {
    const int p = t + i * 256;
    const int qv = p >> 4, n4 = (p & 15) * 4;
    const float4 v = *(const float4*)&smf[p * 4];
    union { u16 u[4]; uint2 q; } h4, l4;
    split2(v.x, h4.u[0], l4.u[0]);
    split2(v.y, h4.u[1], l4.u[1]);
    split2(v.z, h4.u[2], l4.u[2]);
    split2(v.w, h4.u[3], l4.u[3]);
    const size_t off = (size_t)(bI * kS + q0 + qv) * kD + h * 64 + n4;
    *(uint2*)&AoHi[off] = h4.q;
    *(uint2*)&AoLo[off] = l4.q;
  }
}

}  // namespace

extern "C" void kernel_launch(void* const* d_in, const int* in_sizes, int n_in,
                              void* d_out, int out_size, void* d_ws,
                              size_t ws_size, hipStream_t stream) {
  (void)in_sizes; (void)n_in; (void)out_size; (void)ws_size;
  const float* q  = (const float*)d_in[0];
  const float* k  = (const float*)d_in[1];
  const float* v  = (const float*)d_in[2];
  const float* Wq = (const float*)d_in[3];
  const float* bq = (const float*)d_in[4];
  const float* Wk = (const float*)d_in[5];
  const float* bk = (const float*)d_in[6];
  const float* Wv = (const float*)d_in[7];
  const float* bv = (const float*)d_in[8];
  const float* Wo = (const float*)d_in[9];
  const float* bo = (const float*)d_in[10];
  float* out = (float*)d_out;

  // Workspace (u16 units).  hE = 16*4096*64 = 4,194,304 u16 = 8.39 MB.
  // 8 hE regions R0..R7 (67.1 MB) + 8 weight arrays (4.2 MB) + Rl (256 KB)
  // = ~71.5 MB peak.  Regions are time-shared:
  //   R0,R1: split of the CURRENT projection input (q, then k, then v),
  //          then V' (vtrans output) for attn.
  //   R2,R3: Q hi/lo (projected)          -- live through attn
  //   R4,R5: K hi/lo (projected)          -- live through attn
  //   R6,R7: Vrm fp32 (gemmV out), then AttnOut hi/lo
  const size_t hE = (size_t)kBH * kS * 64;
  const size_t wE = (size_t)kD * kD;  // 262,144
  u16* ws = (u16*)d_ws;
  u16* R0 = ws;
  u16* R1 = R0 + hE;
  u16* R2 = R1 + hE;
  u16* R3 = R2 + hE;
  u16* R4 = R3 + hE;
  u16* R5 = R4 + hE;
  u16* R6 = R5 + hE;
  u16* R7 = R6 + hE;
  u16* wtqH = R7 + hE;     u16* wtqL = wtqH + wE;
  u16* wtkH = wtqL + wE;   u16* wtkL = wtkH + wE;
  u16* wtvH = wtkL + wE;   u16* wtvL = wtvH + wE;
  u16* wtoH = wtvL + wE;   u16* wtoL = wtoH + wE;
  float* Rl = (float*)(wtoL + wE);

  float* Vrm = (float*)R6;  // hE floats spans R6+R7

  const dim3 gGrid(kD / 64, (kB * kS) / 128);  // (8, 64)
  const dim3 tGrid(8, 8);

  splitT_kernel<<<tGrid, 256, 0, stream>>>(Wq, wtqH, wtqL);
  splitT_kernel<<<tGrid, 256, 0, stream>>>(Wk, wtkH, wtkL);
  splitT_kernel<<<tGrid, 256, 0, stream>>>(Wv, wtvH, wtvL);
  splitT_kernel<<<tGrid, 256, 0, stream>>>(Wo, wtoH, wtoL);

  split_kernel<<<4096, 256, 0, stream>>>(q, R0, R1);
  mfma_gemm_kernel<0><<<gGrid, 256, 0, stream>>>(R0, R1, wtqH, wtqL, bq,
                                                 R2, R3, nullptr);
  split_kernel<<<4096, 256, 0, stream>>>(k, R0, R1);
  mfma_gemm_kernel<0><<<gGrid, 256, 0, stream>>>(R0, R1, wtkH, wtkL, bk,
                                                 R4, R5, nullptr);
  split_kernel<<<4096, 256, 0, stream>>>(v, R0, R1);
  mfma_gemm_kernel<1><<<gGrid, 256, 0, stream>>>(R0, R1, wtvH, wtvL, bv,
                                                 nullptr, nullptr, Vrm);
  colstats_kernel<<<1024, 256, 0, stream>>>(R2, R3, R4, R5, Rl);
  vtrans_kernel<<<dim3(64, 16), 256, 0, stream>>>(Vrm, Rl, R0, R1);
  attn_kernel<<<512, 256, 0, stream>>>(R2, R3, R4, R5, R0, R1, R6, R7);
  mfma_gemm_kernel<1><<<gGrid, 256, 0, stream>>>(R6, R7, wtoH, wtoL, bo,
                                                 nullptr, nullptr, out);
}